// Round 1
// baseline (52.705 us; speedup 1.0000x reference)
//
#include <hip/hip_runtime.h>
#include <math.h>

#define BB 4
#define NN 1024
#define MM 1024
#define HH 64
#define NCH 64            // number of n-chunks in the main kernel
#define CH (NN / NCH)     // 16 keys per chunk

static constexpr float LOG2E = 1.4426950408889634f;
static constexpr float NEG_BIG = -3.0e38f;

// ---------------- Kernel 1: K and Q MLPs ----------------
// grid (16, 8, 2), block 256.
// Each thread: one row (of 4096), 8 of the 64 outputs (chunk = blockIdx.y).
// type 0 = K (coords_f), type 1 = Q (coords_t). IK == IQ == 3.
__global__ __launch_bounds__(256)
void mlp_kq_kernel(const float* __restrict__ coords_f,
                   const float* __restrict__ coords_t,
                   const float* __restrict__ Wk1, const float* __restrict__ bk1,
                   const float* __restrict__ Wk2, const float* __restrict__ bk2,
                   const float* __restrict__ Wq1, const float* __restrict__ bq1,
                   const float* __restrict__ Wq2, const float* __restrict__ bq2,
                   float* __restrict__ Kout, float* __restrict__ Qout) {
    const int type = blockIdx.z;
    const float* in = (type == 0) ? coords_f : coords_t;
    const float* W1 = (type == 0) ? Wk1 : Wq1;
    const float* b1 = (type == 0) ? bk1 : bq1;
    const float* W2 = (type == 0) ? Wk2 : Wq2;
    const float* b2 = (type == 0) ? bk2 : bq2;
    float* out = (type == 0) ? Kout : Qout;

    const int row = blockIdx.x * 256 + threadIdx.x;   // 0..4095
    const int co  = blockIdx.y * 8;                   // output sub-chunk

    const float in0 = in[row * 3 + 0];
    const float in1 = in[row * 3 + 1];
    const float in2 = in[row * 3 + 2];

    float acc[8];
#pragma unroll
    for (int j = 0; j < 8; ++j) acc[j] = b2[co + j];

    for (int hi = 0; hi < HH; ++hi) {
        float h = b1[hi];
        h = fmaf(in0, W1[hi], h);
        h = fmaf(in1, W1[64 + hi], h);
        h = fmaf(in2, W1[128 + hi], h);
        h = fmaxf(h, 0.0f);
        const float* w = W2 + hi * 64 + co;   // uniform across lanes -> scalar loads
#pragma unroll
        for (int j = 0; j < 8; ++j) acc[j] = fmaf(h, w[j], acc[j]);
    }
#pragma unroll
    for (int j = 0; j < 8; ++j) out[row * 64 + co + j] = acc[j];
}

// ---------------- Kernel 2: vhat = V . Wo (Wo folded through the V-MLP) ----------------
// vhat[row] = relu(x@Wv1+bv1) @ (Wv2@Wo) + bv2.Wo      (exactly V[row,:].Wo)
// grid (16), block 256.
__global__ __launch_bounds__(256)
void vhat_kernel(const float* __restrict__ values_f,
                 const float* __restrict__ Wv1, const float* __restrict__ bv1,
                 const float* __restrict__ Wv2, const float* __restrict__ bv2,
                 const float* __restrict__ Wo,
                 float* __restrict__ vhat) {
    __shared__ float w2o[64];
    __shared__ float b2o_sh;
    const int tid = threadIdx.x;
    if (tid < 64) {
        float s = 0.0f;
        for (int ho = 0; ho < 64; ++ho) s = fmaf(Wv2[tid * 64 + ho], Wo[ho], s);
        w2o[tid] = s;
    }
    if (tid == 0) {
        float s = 0.0f;
        for (int ho = 0; ho < 64; ++ho) s = fmaf(bv2[ho], Wo[ho], s);
        b2o_sh = s;
    }
    __syncthreads();

    const int row = blockIdx.x * 256 + tid;   // 0..4095
    const float* vin = values_f + row * 5;
    const float i0 = vin[0], i1 = vin[1], i2 = vin[2], i3 = vin[3], i4 = vin[4];

    float s = b2o_sh;
    for (int j = 0; j < HH; ++j) {
        float h = bv1[j];
        h = fmaf(i0, Wv1[j], h);
        h = fmaf(i1, Wv1[64 + j], h);
        h = fmaf(i2, Wv1[128 + j], h);
        h = fmaf(i3, Wv1[192 + j], h);
        h = fmaf(i4, Wv1[256 + j], h);
        h = fmaxf(h, 0.0f);
        s = fmaf(h, w2o[j], s);
    }
    vhat[row] = s;
}

// ---------------- Kernel 3: L1 distance + online-softmax partials ----------------
// grid (MM/256, NCH, BB), block 256. Thread owns one m; Q[m,:] in 64 VGPRs.
// K chunk (16 rows x 64) staged in LDS, read with uniform addresses (broadcast).
__global__ __launch_bounds__(256)
void dist_partial_kernel(const float* __restrict__ Kb,
                         const float* __restrict__ Qb,
                         const float* __restrict__ vhat,
                         float* __restrict__ mx_out,
                         float* __restrict__ den_out,
                         float* __restrict__ num_out) {
    __shared__ float kt[CH * 64];   // 4 KB
    __shared__ float vt[CH];

    const int tid = threadIdx.x;
    const int b = blockIdx.z;
    const int c = blockIdx.y;
    const int m = blockIdx.x * 256 + tid;

    // stage K tile: CH*64 = 1024 floats = 256 float4, one per thread (coalesced)
    const float4* ksrc = reinterpret_cast<const float4*>(Kb + (b * NN + c * CH) * 64);
    reinterpret_cast<float4*>(kt)[tid] = ksrc[tid];
    if (tid < CH) vt[tid] = vhat[b * NN + c * CH + tid];
    __syncthreads();

    // Q row into registers
    float4 q[16];
    const float4* qsrc = reinterpret_cast<const float4*>(Qb + (b * MM + m) * 64);
#pragma unroll
    for (int i = 0; i < 16; ++i) q[i] = qsrc[i];

    float mx = NEG_BIG, den = 0.0f, num = 0.0f;

    for (int n = 0; n < CH; ++n) {
        const float4* kr = reinterpret_cast<const float4*>(kt + n * 64);
        // 4 partial sums to break the serial add chain
        float d0 = 0.0f, d1 = 0.0f, d2 = 0.0f, d3 = 0.0f;
#pragma unroll
        for (int i = 0; i < 16; ++i) {
            float4 k4 = kr[i];   // uniform LDS address -> broadcast, conflict-free
            d0 += fabsf(k4.x - q[i].x);
            d1 += fabsf(k4.y - q[i].y);
            d2 += fabsf(k4.z - q[i].z);
            d3 += fabsf(k4.w - q[i].w);
        }
        const float d = (d0 + d1) + (d2 + d3);
        const float a = d * d * (-0.5f * LOG2E);   // score in log2 domain
        const float nm = fmaxf(mx, a);
        const float s0 = exp2f(mx - nm);           // 1 unless new max
        const float p  = exp2f(a - nm);
        den = fmaf(den, s0, p);
        num = fmaf(num, s0, p * vt[n]);
        mx = nm;
    }

    const int pidx = c * (BB * MM) + b * MM + m;   // [c][b][m] -> coalesced
    mx_out[pidx]  = mx;
    den_out[pidx] = den;
    num_out[pidx] = num;
}

// ---------------- Kernel 4: combine partials over chunks ----------------
// grid (16), block 256: thread per (b,m).
__global__ __launch_bounds__(256)
void combine_kernel(const float* __restrict__ mx_in,
                    const float* __restrict__ den_in,
                    const float* __restrict__ num_in,
                    const float* __restrict__ bo,
                    float* __restrict__ out) {
    const int bm = blockIdx.x * 256 + threadIdx.x;   // 0..4095 == b*MM + m
    float M = NEG_BIG, den = 0.0f, num = 0.0f;
    for (int c = 0; c < NCH; ++c) {
        const int idx = c * (BB * MM) + bm;
        const float mxc = mx_in[idx];
        const float nm = fmaxf(M, mxc);
        const float s0 = exp2f(M - nm);
        const float s1 = exp2f(mxc - nm);
        den = den * s0 + den_in[idx] * s1;
        num = num * s0 + num_in[idx] * s1;
        M = nm;
    }
    out[bm] = num / den + bo[0];
}

// ---------------- launcher ----------------
extern "C" void kernel_launch(void* const* d_in, const int* in_sizes, int n_in,
                              void* d_out, int out_size, void* d_ws, size_t ws_size,
                              hipStream_t stream) {
    const float* coords_f = (const float*)d_in[0];
    const float* values_f = (const float*)d_in[1];
    const float* coords_t = (const float*)d_in[2];
    const float* Wk1 = (const float*)d_in[3];
    const float* bk1 = (const float*)d_in[4];
    const float* Wk2 = (const float*)d_in[5];
    const float* bk2 = (const float*)d_in[6];
    const float* Wq1 = (const float*)d_in[7];
    const float* bq1 = (const float*)d_in[8];
    const float* Wq2 = (const float*)d_in[9];
    const float* bq2 = (const float*)d_in[10];
    const float* Wv1 = (const float*)d_in[11];
    const float* bv1 = (const float*)d_in[12];
    const float* Wv2 = (const float*)d_in[13];
    const float* bv2 = (const float*)d_in[14];
    const float* Wo  = (const float*)d_in[15];
    const float* bo  = (const float*)d_in[16];

    float* ws   = (float*)d_ws;
    float* Kb   = ws;                      // B*N*H   = 262144
    float* Qb   = Kb + BB * NN * HH;       // B*M*H   = 262144
    float* vh   = Qb + BB * MM * HH;       // B*N     = 4096
    float* mx   = vh + BB * NN;            // B*M*NCH = 262144
    float* den  = mx + BB * MM * NCH;
    float* num  = den + BB * MM * NCH;
    // total ~5.3 MB of workspace

    mlp_kq_kernel<<<dim3(16, 8, 2), 256, 0, stream>>>(
        coords_f, coords_t, Wk1, bk1, Wk2, bk2, Wq1, bq1, Wq2, bq2, Kb, Qb);

    vhat_kernel<<<dim3(16), 256, 0, stream>>>(
        values_f, Wv1, bv1, Wv2, bv2, Wo, vh);

    dist_partial_kernel<<<dim3(MM / 256, NCH, BB), 256, 0, stream>>>(
        Kb, Qb, vh, mx, den, num);

    combine_kernel<<<dim3(16), 256, 0, stream>>>(mx, den, num, bo, (float*)d_out);
}